// Round 20
// baseline (54.851 us; speedup 1.0000x reference)
//
#include <hip/hip_runtime.h>
#include <hip/hip_bf16.h>
#include <math.h>

#define BS 8
#define NN 1024
#define FIN 256
#define HEADS 8
#define FO 64
#define NH (HEADS*FO)   /* 512 */
static constexpr float ALPHA = 0.2f;
static constexpr float LOG2E = 1.4426950408889634f;

typedef short bf16x8 __attribute__((ext_vector_type(8)));
typedef float f32x4  __attribute__((ext_vector_type(4)));
typedef float f32x2  __attribute__((ext_vector_type(2)));
typedef unsigned short u16;
typedef unsigned u32;
typedef u16 u16x4v __attribute__((ext_vector_type(4)));
typedef u16 u16x8v __attribute__((ext_vector_type(8)));

__device__ __forceinline__ u16 f2b(float x) {
    __hip_bfloat16 b = __float2bfloat16(x);
    return *reinterpret_cast<u16*>(&b);
}
__device__ __forceinline__ float fexp2(float x) {
#if __has_builtin(__builtin_amdgcn_exp2f)
    return __builtin_amdgcn_exp2f(x);
#else
    float r; asm("v_exp_f32 %0, %1" : "=v"(r) : "v"(x)); return r;
#endif
}
__device__ __forceinline__ void gload_lds16(const void* g, void* l) {
    __builtin_amdgcn_global_load_lds(
        (const __attribute__((address_space(1))) unsigned int*)g,
        (__attribute__((address_space(3))) unsigned int*)l, 16, 0, 0);
}

// ---------------------------------------------------------------------------
// cvt: {cvt_h | cvt_wT}. 1024 + 32 blocks. Produces gemm inputs only.
// ---------------------------------------------------------------------------
__global__ __launch_bounds__(256) void cvt(const float* __restrict__ h,
                                           const float* __restrict__ W,
                                           u16* __restrict__ hb,
                                           u16* __restrict__ WbT) {
    const int bid = blockIdx.x;
    const int t = threadIdx.x;
    if (bid < 1024) {
        const int i = (bid * 256 + t) * 8;
        const float4 v0 = *reinterpret_cast<const float4*>(h + i);
        const float4 v1 = *reinterpret_cast<const float4*>(h + i + 4);
        u16x8v o;
        o[0]=f2b(v0.x); o[1]=f2b(v0.y); o[2]=f2b(v0.z); o[3]=f2b(v0.w);
        o[4]=f2b(v1.x); o[5]=f2b(v1.y); o[6]=f2b(v1.z); o[7]=f2b(v1.w);
        *reinterpret_cast<u16x8v*>(hb + i) = o;
    } else {
        __shared__ float T[64][65];
        const int bb = bid - 1024;
        const int hh = bb & 7;
        const int n0 = hh * 64, k0 = (bb >> 3) * 64;
        const int r4 = t >> 6, c = t & 63;
        #pragma unroll
        for (int p = 0; p < 16; ++p) {
            const int r = p * 4 + r4;
            T[r][c] = W[(size_t)(k0 + r) * NH + n0 + c];
        }
        __syncthreads();
        #pragma unroll
        for (int p = 0; p < 16; ++p) {
            const int r = p * 4 + r4;
            WbT[(size_t)(n0 + r) * FIN + k0 + c] = f2b(T[c][r]);
        }
    }
}

// ---------------------------------------------------------------------------
// gemm_pack: fused {gemm_whT | pack_adj}, grid 9216. bid%9==0 -> gemm
// (1024 blocks, 64x64 tile, XCD-chunked), else -> pack_adj (8192 blocks).
// Round-robin dispatch co-schedules the BW-bound adj scan under the
// compute-bound GEMM.
// ---------------------------------------------------------------------------
__global__ __launch_bounds__(256) void gemm_pack(const u16* __restrict__ hb,
                                                 const u16* __restrict__ WbT,
                                                 const float* __restrict__ avec,
                                                 const int* __restrict__ adj,
                                                 u16* __restrict__ WhT,
                                                 float* __restrict__ esrc,
                                                 float* __restrict__ edst,
                                                 u32* __restrict__ bits) {
    __shared__ u16 Al[2][64 * 64];
    __shared__ u16 Bl[2][64 * 64];
    const int bid = blockIdx.x;
    const int t = threadIdx.x;

    if (bid % 9 != 0) {
        // ---- pack_adj: 4 elems/lane (int4) + shuffle-assemble ----
        const int pid = bid - (bid / 9) - 1;
        const int lane = t & 63;
        const size_t e0 = ((size_t)pid * 256 + t) * 4;
        const int4 v = *reinterpret_cast<const int4*>(adj + e0);
        u32 x = (v.x ? 1u : 0u) | (v.y ? 2u : 0u) | (v.z ? 4u : 0u) | (v.w ? 8u : 0u);
        {   const u32 r = (u32)__shfl_xor((int)x, 1);
            const int sh = (lane & 1) * 4;  x = (x << sh) | (r << (4 - sh)); }
        {   const u32 r = (u32)__shfl_xor((int)x, 2);
            const int sh = (lane & 2) * 4;  x = (x << sh) | (r << (8 - sh)); }
        {   const u32 r = (u32)__shfl_xor((int)x, 4);
            const int sh = (lane & 4) * 4;  x = (x << sh) | (r << (16 - sh)); }
        if ((lane & 7) == 0) bits[e0 >> 5] = x;
        return;
    }

    // ---- gemm path ----
    const int gb = bid / 9;                    // 0..1023
    const int wv = t >> 6, lane = t & 63;
    const int g = lane >> 4, l15 = lane & 15;
    const int lid = (gb & 7) * 128 + (gb >> 3);
    const int m0 = (lid >> 3) * 64;
    const int h  = lid & 7;
    const int lr = lane >> 3;
    const int sch = (lane & 7) ^ lr;
    const int bh = (m0 >> 10) * HEADS + h;

    f32x4 acc[4] = {};

    auto stageA = [&](int buf, int k0) {
        #pragma unroll
        for (int c = 0; c < 2; ++c) {
            const int rowb = wv * 16 + c * 8;
            gload_lds16(hb + (size_t)(m0 + rowb + lr) * FIN + k0 + sch * 8,
                        &Al[buf][rowb * 64]);
        }
    };
    auto stageB = [&](int buf, int k0) {
        #pragma unroll
        for (int c = 0; c < 2; ++c) {
            const int rowb = wv * 16 + c * 8;
            gload_lds16(WbT + (size_t)(h * 64 + rowb + lr) * FIN + k0 + sch * 8,
                        &Bl[buf][rowb * 64]);
        }
    };

    stageA(0, 0); stageB(0, 0);
    __syncthreads();
    for (int kt = 0; kt < 4; ++kt) {
        const int buf = kt & 1;
        if (kt < 3) { stageA(buf ^ 1, (kt + 1) * 64); stageB(buf ^ 1, (kt + 1) * 64); }
        #pragma unroll
        for (int ks = 0; ks < 2; ++ks) {
            const int ch = (ks * 4 + g) ^ (l15 & 7);
            const bf16x8 afr = *reinterpret_cast<const bf16x8*>(
                &Al[buf][(wv * 16 + l15) * 64 + ch * 8]);
            #pragma unroll
            for (int n = 0; n < 4; ++n) {
                const bf16x8 bfr = *reinterpret_cast<const bf16x8*>(
                    &Bl[buf][(n * 16 + l15) * 64 + ch * 8]);
                acc[n] = __builtin_amdgcn_mfma_f32_16x16x32_bf16(afr, bfr, acc[n], 0, 0, 0);
            }
        }
        __syncthreads();
    }

    // ---- e epilogue (exact f32, exp2 domain) ----
    {
        float as_[4], ad_[4];
        #pragma unroll
        for (int n = 0; n < 4; ++n) {
            as_[n] = avec[h * 128 + n * 16 + l15] * LOG2E;
            ad_[n] = avec[h * 128 + 64 + n * 16 + l15] * LOG2E;
        }
        #pragma unroll
        for (int r = 0; r < 4; ++r) {
            float ps = acc[0][r] * as_[0] + acc[1][r] * as_[1]
                     + acc[2][r] * as_[2] + acc[3][r] * as_[3];
            float pd = acc[0][r] * ad_[0] + acc[1][r] * ad_[1]
                     + acc[2][r] * ad_[2] + acc[3][r] * ad_[3];
            #pragma unroll
            for (int off = 1; off < 16; off <<= 1) {
                ps += __shfl_xor(ps, off);
                pd += __shfl_xor(pd, off);
            }
            if (l15 == 0) {
                const int i = (m0 + wv * 16 + g * 4 + r) & (NN - 1);
                esrc[(size_t)bh * NN + i] = ps;
                edst[(size_t)bh * NN + i] = pd;
            }
        }
    }

    // ---- WhT store via LDS bounce (coalesced) ----
    u16* scr = &Al[0][0];
    #pragma unroll
    for (int n = 0; n < 4; ++n) {
        u16x4v pk;
        #pragma unroll
        for (int r = 0; r < 4; ++r) pk[r] = f2b(acc[n][r]);
        *reinterpret_cast<u16x4v*>(&scr[(n * 16 + l15) * 72 + wv * 16 + g * 4]) = pk;
    }
    __syncthreads();
    const int il0 = m0 & (NN - 1);
    const int f = t >> 2, q = t & 3;
    const u16x8v v0 = *reinterpret_cast<const u16x8v*>(&scr[f * 72 + q * 16]);
    const u16x8v v1 = *reinterpret_cast<const u16x8v*>(&scr[f * 72 + q * 16 + 8]);
    u16* dst = &WhT[((size_t)bh * 64 + f) * NN + il0 + q * 16];
    *reinterpret_cast<u16x8v*>(dst)     = v0;
    *reinterpret_cast<u16x8v*>(dst + 8) = v1;
}

// ---------------------------------------------------------------------------
// attn_pv (r16 best-known): 256 thr / 4 waves / 128 rows, dual-A, 16KB dbuf,
// grid 512, counted vmcnt(8) barrier, setprio, packed-f32 p-gen, dsum MFMA.
// ---------------------------------------------------------------------------
__global__ __launch_bounds__(256, 2) void attn_pv(const u32* __restrict__ bits,
                                                  const u16* __restrict__ WhT,
                                                  const float* __restrict__ esrc,
                                                  const float* __restrict__ edst,
                                                  float* __restrict__ out) {
    __shared__ u16 Bs[2][64 * 64];             // 16 KB, V tile dbuf
    const int t = threadIdx.x, wv = t >> 6, lane = t & 63;
    const int g = lane >> 4, l15 = lane & 15;
    const int lr = lane >> 3, sch = (lane & 7) ^ lr;

    // XCD chunk: 64 consecutive lids (8 i-chunks x 8 heads of one batch)/XCD
    const int lid = (blockIdx.x & 7) * 64 + (blockIdx.x >> 3);
    const int it = lid & 7, h = (lid >> 3) & 7, b = lid >> 6;
    const int i0 = it * 128;
    const int bh = b * HEADS + h;
    const int row0 = i0 + wv * 32 + l15;       // mf=0 row; mf=1 at +16

    const float es0 = esrc[(size_t)bh * NN + row0];
    const float es1 = esrc[(size_t)bh * NN + row0 + 16];
    const f32x2 es0v = {es0, es0};
    const f32x2 es1v = {es1, es1};
    const u16*  whb = WhT + (size_t)bh * 64 * NN;
    const float* ed = edst + (size_t)bh * NN + 8 * g;
    const u32*  bitrow0 = bits + (size_t)(b * NN + row0) * 32;
    const u32*  bitrow1 = bitrow0 + 16 * 32;

    auto stage = [&](int buf, int j0) {
        #pragma unroll
        for (int c = 0; c < 2; ++c) {
            const int fb = wv * 16 + c * 8;
            gload_lds16(whb + (size_t)(fb + lr) * NN + j0 + sch * 8,
                        &Bs[buf][fb * 64]);
        }
    };

    stage(0, 0);
    // 2-deep register prefetch slots (slot = parity of step s)
    float4 peA[2], peB[2];
    u32    pw0[2], pw1[2];
    #pragma unroll
    for (int s = 0; s < 2; ++s) {
        peA[s] = *(const float4*)(ed + s * 32);
        peB[s] = *(const float4*)(ed + s * 32 + 4);
        pw0[s] = bitrow0[s];
        pw1[s] = bitrow1[s];
    }
    __syncthreads();

    f32x4 acc0[4] = {}, acc1[4] = {};
    f32x4 dsum0 = {}, dsum1 = {};
    bf16x8 ones;
    #pragma unroll
    for (int q = 0; q < 8; ++q) ones[q] = (short)0x3F80;   // bf16(1.0)

    for (int tt = 0; tt < 16; ++tt) {
        const int buf = tt & 1;
        const bool more = (tt < 15);
        if (more) {
            stage(buf ^ 1, (tt + 1) * 64);
            asm volatile("" ::: "memory");     // pin: prefetches stay after stage
        }
        #pragma unroll
        for (int ks = 0; ks < 2; ++ks) {
            const int s = tt * 2 + ks;
            const float4 e0 = peA[ks], e1 = peB[ks];
            const u32 w0 = pw0[ks], w1 = pw1[ks];
            if (more) {                        // refill slot with step s+2
                peA[ks] = *(const float4*)(ed + (s + 2) * 32);
                peB[ks] = *(const float4*)(ed + (s + 2) * 32 + 4);
                pw0[ks] = bitrow0[s + 2];
                pw1[ks] = bitrow1[s + 2];
            }
            // B fragments early: ds latency hides under p-gen
            const int chb = ((ks * 4 + g) ^ (l15 & 7)) * 8;
            const bf16x8 v0 = *(const bf16x8*)(&Bs[buf][(0 * 16 + l15) * 64 + chb]);
            const bf16x8 v1 = *(const bf16x8*)(&Bs[buf][(1 * 16 + l15) * 64 + chb]);
            const bf16x8 v2 = *(const bf16x8*)(&Bs[buf][(2 * 16 + l15) * 64 + chb]);
            const bf16x8 v3 = *(const bf16x8*)(&Bs[buf][(3 * 16 + l15) * 64 + chb]);

            f32x2 ej2[4];
            ej2[0] = f32x2{e0.x, e0.y};
            ej2[1] = f32x2{e0.z, e0.w};
            ej2[2] = f32x2{e1.x, e1.y};
            ej2[3] = f32x2{e1.z, e1.w};
            const u32 by0 = (w0 >> (8 * g)) & 0xffu;
            const u32 by1 = (w1 >> (8 * g)) & 0xffu;

            union { u32 u[4]; bf16x8 v; } af0, af1;
            #pragma unroll
            for (int qp = 0; qp < 4; ++qp) {
                f32x2 s0 = es0v + ej2[qp];
                f32x2 s1 = es1v + ej2[qp];
                s0 = __builtin_elementwise_max(s0, s0 * ALPHA);
                s1 = __builtin_elementwise_max(s1, s1 * ALPHA);
                const float p0a = fexp2(((by0 >> (2*qp))     & 1u) ? s0[0] : -1e30f);
                const float p0b = fexp2(((by0 >> (2*qp + 1)) & 1u) ? s0[1] : -1e30f);
                const float p1a = fexp2(((by1 >> (2*qp))     & 1u) ? s1[0] : -1e30f);
                const float p1b = fexp2(((by1 >> (2*qp + 1)) & 1u) ? s1[1] : -1e30f);
                union { __hip_bfloat162 b2; u32 w; } c0, c1;
                c0.b2 = __float22bfloat162_rn(make_float2(p0a, p0b));
                c1.b2 = __float22bfloat162_rn(make_float2(p1a, p1b));
                af0.u[qp] = c0.w;
                af1.u[qp] = c1.w;
            }
            __builtin_amdgcn_s_setprio(1);
            acc0[0] = __builtin_amdgcn_mfma_f32_16x16x32_bf16(af0.v, v0, acc0[0], 0, 0, 0);
            acc1[0] = __builtin_amdgcn_mfma_f32_16x16x32_bf16(af1.v, v0, acc1[0], 0, 0, 0);
            acc0[1] = __builtin_amdgcn_mfma_f32_16x16x32_bf16(af0.v, v1, acc0[1], 0, 0, 0);
            acc1[1] = __builtin_amdgcn_mfma_f32_16x16x32_bf16(af1.v, v1, acc1[1], 0, 0, 0);
            acc0[2] = __builtin_amdgcn_mfma_f32_16x16x32_bf16(af0.v, v2, acc0[2], 0, 0, 0);
            acc1[2] = __builtin_amdgcn_mfma_f32_16x16x32_bf16(af1.v, v2, acc1[2], 0, 0, 0);
            acc0[3] = __builtin_amdgcn_mfma_f32_16x16x32_bf16(af0.v, v3, acc0[3], 0, 0, 0);
            acc1[3] = __builtin_amdgcn_mfma_f32_16x16x32_bf16(af1.v, v3, acc1[3], 0, 0, 0);
            dsum0   = __builtin_amdgcn_mfma_f32_16x16x32_bf16(af0.v, ones, dsum0, 0, 0, 0);
            dsum1   = __builtin_amdgcn_mfma_f32_16x16x32_bf16(af1.v, ones, dsum1, 0, 0, 0);
            __builtin_amdgcn_s_setprio(0);
        }
        if (more) {
            // per-wave VMEM newer than the last stage load: 8 prefetches
            // -> vmcnt(8) guarantees stage landed, prefetches stay in flight.
            asm volatile("s_waitcnt vmcnt(8)" ::: "memory");
            __builtin_amdgcn_s_barrier();
        }
    }

    float inv0[4], inv1[4];
    #pragma unroll
    for (int r = 0; r < 4; ++r) { inv0[r] = 1.0f / dsum0[r]; inv1[r] = 1.0f / dsum1[r]; }
    #pragma unroll
    for (int n = 0; n < 4; ++n)
        #pragma unroll
        for (int r = 0; r < 4; ++r) {
            const int io0 = i0 + wv * 32 + g * 4 + r;
            out[(size_t)(b * NN + io0) * NH + h * 64 + n * 16 + l15] =
                acc0[n][r] * inv0[r];
            out[(size_t)(b * NN + io0 + 16) * NH + h * 64 + n * 16 + l15] =
                acc1[n][r] * inv1[r];
        }
}

// ---------------------------------------------------------------------------
extern "C" void kernel_launch(void* const* d_in, const int* in_sizes, int n_in,
                              void* d_out, int out_size, void* d_ws, size_t ws_size,
                              hipStream_t stream) {
    const float* h   = (const float*)d_in[0];
    const int*   adj = (const int*)  d_in[1];
    const float* W   = (const float*)d_in[2];
    const float* a   = (const float*)d_in[3];
    float* out = (float*)d_out;

    char* p = (char*)d_ws;
    u16*   hb   = (u16*)p;   p += (size_t)BS * NN * FIN * 2;        // 4 MB
    u16*   WbT  = (u16*)p;   p += (size_t)NH * FIN * 2;             // 256 KB
    u16*   WhT  = (u16*)p;   p += (size_t)BS * HEADS * FO * NN * 2; // 8 MB
    float* esrc = (float*)p; p += (size_t)BS * HEADS * NN * 4;      // 256 KB
    float* edst = (float*)p; p += (size_t)BS * HEADS * NN * 4;      // 256 KB
    u32*   bits = (u32*)p;                                          // 1 MB

    cvt      <<<1056, 256, 0, stream>>>(h, W, hb, WbT);
    gemm_pack<<<9216, 256, 0, stream>>>(hb, WbT, a, adj, WhT, esrc, edst, bits);
    attn_pv  <<<512, 256, 0, stream>>>(bits, WhT, esrc, edst, out);
}

// Round 21
// 50.297 us; speedup vs baseline: 1.0905x; 1.0905x over previous
//
#include <hip/hip_runtime.h>
#include <hip/hip_bf16.h>
#include <math.h>

#define BS 8
#define NN 1024
#define FIN 256
#define HEADS 8
#define FO 64
#define NH (HEADS*FO)   /* 512 */
static constexpr float ALPHA = 0.2f;
static constexpr float LOG2E = 1.4426950408889634f;

typedef short bf16x8 __attribute__((ext_vector_type(8)));
typedef float f32x4  __attribute__((ext_vector_type(4)));
typedef float f32x2  __attribute__((ext_vector_type(2)));
typedef unsigned short u16;
typedef unsigned u32;
typedef u16 u16x4v __attribute__((ext_vector_type(4)));
typedef u16 u16x8v __attribute__((ext_vector_type(8)));

__device__ __forceinline__ u16 f2b(float x) {
    __hip_bfloat16 b = __float2bfloat16(x);
    return *reinterpret_cast<u16*>(&b);
}
__device__ __forceinline__ float fexp2(float x) {
#if __has_builtin(__builtin_amdgcn_exp2f)
    return __builtin_amdgcn_exp2f(x);
#else
    float r; asm("v_exp_f32 %0, %1" : "=v"(r) : "v"(x)); return r;
#endif
}
__device__ __forceinline__ void gload_lds16(const void* g, void* l) {
    __builtin_amdgcn_global_load_lds(
        (const __attribute__((address_space(1))) unsigned int*)g,
        (__attribute__((address_space(3))) unsigned int*)l, 16, 0, 0);
}

// ---------------------------------------------------------------------------
// prep_misc: fused {pack_adj | cvt_h | cvt_wT}. 8192 + 1024 + 32 blocks.
// ---------------------------------------------------------------------------
__global__ __launch_bounds__(256) void prep_misc(const float* __restrict__ h,
                                                 const int* __restrict__ adj,
                                                 const float* __restrict__ W,
                                                 u16* __restrict__ hb,
                                                 u16* __restrict__ WbT,
                                                 u32* __restrict__ bits) {
    const int bid = blockIdx.x;
    const int t = threadIdx.x;
    if (bid < 8192) {
        const int lane = t & 63;
        const size_t e0 = ((size_t)bid * 256 + t) * 4;
        const int4 v = *reinterpret_cast<const int4*>(adj + e0);
        u32 x = (v.x ? 1u : 0u) | (v.y ? 2u : 0u) | (v.z ? 4u : 0u) | (v.w ? 8u : 0u);
        {   const u32 r = (u32)__shfl_xor((int)x, 1);
            const int sh = (lane & 1) * 4;  x = (x << sh) | (r << (4 - sh)); }
        {   const u32 r = (u32)__shfl_xor((int)x, 2);
            const int sh = (lane & 2) * 4;  x = (x << sh) | (r << (8 - sh)); }
        {   const u32 r = (u32)__shfl_xor((int)x, 4);
            const int sh = (lane & 4) * 4;  x = (x << sh) | (r << (16 - sh)); }
        if ((lane & 7) == 0) bits[e0 >> 5] = x;
    } else if (bid < 9216) {
        const int i = ((bid - 8192) * 256 + t) * 8;
        const float4 v0 = *reinterpret_cast<const float4*>(h + i);
        const float4 v1 = *reinterpret_cast<const float4*>(h + i + 4);
        u16x8v o;
        o[0]=f2b(v0.x); o[1]=f2b(v0.y); o[2]=f2b(v0.z); o[3]=f2b(v0.w);
        o[4]=f2b(v1.x); o[5]=f2b(v1.y); o[6]=f2b(v1.z); o[7]=f2b(v1.w);
        *reinterpret_cast<u16x8v*>(hb + i) = o;
    } else {
        __shared__ float T[64][65];
        const int bb = bid - 9216;
        const int hh = bb & 7;
        const int n0 = hh * 64, k0 = (bb >> 3) * 64;
        const int r4 = t >> 6, c = t & 63;
        #pragma unroll
        for (int p = 0; p < 16; ++p) {
            const int r = p * 4 + r4;
            T[r][c] = W[(size_t)(k0 + r) * NH + n0 + c];
        }
        __syncthreads();
        #pragma unroll
        for (int p = 0; p < 16; ++p) {
            const int r = p * 4 + r4;
            WbT[(size_t)(n0 + r) * FIN + k0 + c] = f2b(T[c][r]);
        }
    }
}

// ---------------------------------------------------------------------------
// gemm_whT: Wh = hb @ WbT^T, 64x64 tile, grid 1024, XCD-chunked.
// Epilogue: exact-f32 e_src/e_dst from accumulators + transposed bf16 WhT.
// ---------------------------------------------------------------------------
__global__ __launch_bounds__(256) void gemm_whT(const u16* __restrict__ hb,
                                                const u16* __restrict__ WbT,
                                                const float* __restrict__ avec,
                                                u16* __restrict__ WhT,
                                                float* __restrict__ esrc,
                                                float* __restrict__ edst) {
    __shared__ u16 Al[2][64 * 64];
    __shared__ u16 Bl[2][64 * 64];
    const int t = threadIdx.x, wv = t >> 6, lane = t & 63;
    const int g = lane >> 4, l15 = lane & 15;
    const int lid = (blockIdx.x & 7) * 128 + (blockIdx.x >> 3);
    const int m0 = (lid >> 3) * 64;
    const int h  = lid & 7;
    const int lr = lane >> 3;
    const int sch = (lane & 7) ^ lr;
    const int bh = (m0 >> 10) * HEADS + h;

    f32x4 acc[4] = {};

    auto stageA = [&](int buf, int k0) {
        #pragma unroll
        for (int c = 0; c < 2; ++c) {
            const int rowb = wv * 16 + c * 8;
            gload_lds16(hb + (size_t)(m0 + rowb + lr) * FIN + k0 + sch * 8,
                        &Al[buf][rowb * 64]);
        }
    };
    auto stageB = [&](int buf, int k0) {
        #pragma unroll
        for (int c = 0; c < 2; ++c) {
            const int rowb = wv * 16 + c * 8;
            gload_lds16(WbT + (size_t)(h * 64 + rowb + lr) * FIN + k0 + sch * 8,
                        &Bl[buf][rowb * 64]);
        }
    };

    stageA(0, 0); stageB(0, 0);
    __syncthreads();
    for (int kt = 0; kt < 4; ++kt) {
        const int buf = kt & 1;
        if (kt < 3) { stageA(buf ^ 1, (kt + 1) * 64); stageB(buf ^ 1, (kt + 1) * 64); }
        #pragma unroll
        for (int ks = 0; ks < 2; ++ks) {
            const int ch = (ks * 4 + g) ^ (l15 & 7);
            const bf16x8 afr = *reinterpret_cast<const bf16x8*>(
                &Al[buf][(wv * 16 + l15) * 64 + ch * 8]);
            #pragma unroll
            for (int n = 0; n < 4; ++n) {
                const bf16x8 bfr = *reinterpret_cast<const bf16x8*>(
                    &Bl[buf][(n * 16 + l15) * 64 + ch * 8]);
                acc[n] = __builtin_amdgcn_mfma_f32_16x16x32_bf16(afr, bfr, acc[n], 0, 0, 0);
            }
        }
        __syncthreads();
    }

    // ---- e epilogue (exact f32, exp2 domain) ----
    {
        float as_[4], ad_[4];
        #pragma unroll
        for (int n = 0; n < 4; ++n) {
            as_[n] = avec[h * 128 + n * 16 + l15] * LOG2E;
            ad_[n] = avec[h * 128 + 64 + n * 16 + l15] * LOG2E;
        }
        #pragma unroll
        for (int r = 0; r < 4; ++r) {
            float ps = acc[0][r] * as_[0] + acc[1][r] * as_[1]
                     + acc[2][r] * as_[2] + acc[3][r] * as_[3];
            float pd = acc[0][r] * ad_[0] + acc[1][r] * ad_[1]
                     + acc[2][r] * ad_[2] + acc[3][r] * ad_[3];
            #pragma unroll
            for (int off = 1; off < 16; off <<= 1) {
                ps += __shfl_xor(ps, off);
                pd += __shfl_xor(pd, off);
            }
            if (l15 == 0) {
                const int i = (m0 + wv * 16 + g * 4 + r) & (NN - 1);
                esrc[(size_t)bh * NN + i] = ps;
                edst[(size_t)bh * NN + i] = pd;
            }
        }
    }

    // ---- WhT store via LDS bounce (coalesced) ----
    u16* scr = &Al[0][0];
    #pragma unroll
    for (int n = 0; n < 4; ++n) {
        u16x4v pk;
        #pragma unroll
        for (int r = 0; r < 4; ++r) pk[r] = f2b(acc[n][r]);
        *reinterpret_cast<u16x4v*>(&scr[(n * 16 + l15) * 72 + wv * 16 + g * 4]) = pk;
    }
    __syncthreads();
    const int il0 = m0 & (NN - 1);
    const int f = t >> 2, q = t & 3;
    const u16x8v v0 = *reinterpret_cast<const u16x8v*>(&scr[f * 72 + q * 16]);
    const u16x8v v1 = *reinterpret_cast<const u16x8v*>(&scr[f * 72 + q * 16 + 8]);
    u16* dst = &WhT[((size_t)bh * 64 + f) * NN + il0 + q * 16];
    *reinterpret_cast<u16x8v*>(dst)     = v0;
    *reinterpret_cast<u16x8v*>(dst + 8) = v1;
}

// ---------------------------------------------------------------------------
// attn_pv (final, r16): 256 thr / 4 waves / 128 rows, dual-A (each B-frag
// ds_read feeds 2 MFMAs), 16KB V dbuf, grid 512 XCD-chunked, counted
// vmcnt(8) raw barrier, setprio MFMA cluster, packed-f32 p-gen, dsum MFMA.
// ---------------------------------------------------------------------------
__global__ __launch_bounds__(256, 2) void attn_pv(const u32* __restrict__ bits,
                                                  const u16* __restrict__ WhT,
                                                  const float* __restrict__ esrc,
                                                  const float* __restrict__ edst,
                                                  float* __restrict__ out) {
    __shared__ u16 Bs[2][64 * 64];             // 16 KB, V tile dbuf
    const int t = threadIdx.x, wv = t >> 6, lane = t & 63;
    const int g = lane >> 4, l15 = lane & 15;
    const int lr = lane >> 3, sch = (lane & 7) ^ lr;

    // XCD chunk: 64 consecutive lids (8 i-chunks x 8 heads of one batch)/XCD
    const int lid = (blockIdx.x & 7) * 64 + (blockIdx.x >> 3);
    const int it = lid & 7, h = (lid >> 3) & 7, b = lid >> 6;
    const int i0 = it * 128;
    const int bh = b * HEADS + h;
    const int row0 = i0 + wv * 32 + l15;       // mf=0 row; mf=1 at +16

    const float es0 = esrc[(size_t)bh * NN + row0];
    const float es1 = esrc[(size_t)bh * NN + row0 + 16];
    const f32x2 es0v = {es0, es0};
    const f32x2 es1v = {es1, es1};
    const u16*  whb = WhT + (size_t)bh * 64 * NN;
    const float* ed = edst + (size_t)bh * NN + 8 * g;
    const u32*  bitrow0 = bits + (size_t)(b * NN + row0) * 32;
    const u32*  bitrow1 = bitrow0 + 16 * 32;

    auto stage = [&](int buf, int j0) {
        #pragma unroll
        for (int c = 0; c < 2; ++c) {
            const int fb = wv * 16 + c * 8;
            gload_lds16(whb + (size_t)(fb + lr) * NN + j0 + sch * 8,
                        &Bs[buf][fb * 64]);
        }
    };

    stage(0, 0);
    // 2-deep register prefetch slots (slot = parity of step s)
    float4 peA[2], peB[2];
    u32    pw0[2], pw1[2];
    #pragma unroll
    for (int s = 0; s < 2; ++s) {
        peA[s] = *(const float4*)(ed + s * 32);
        peB[s] = *(const float4*)(ed + s * 32 + 4);
        pw0[s] = bitrow0[s];
        pw1[s] = bitrow1[s];
    }
    __syncthreads();

    f32x4 acc0[4] = {}, acc1[4] = {};
    f32x4 dsum0 = {}, dsum1 = {};
    bf16x8 ones;
    #pragma unroll
    for (int q = 0; q < 8; ++q) ones[q] = (short)0x3F80;   // bf16(1.0)

    for (int tt = 0; tt < 16; ++tt) {
        const int buf = tt & 1;
        const bool more = (tt < 15);
        if (more) {
            stage(buf ^ 1, (tt + 1) * 64);
            asm volatile("" ::: "memory");     // pin: prefetches stay after stage
        }
        #pragma unroll
        for (int ks = 0; ks < 2; ++ks) {
            const int s = tt * 2 + ks;
            const float4 e0 = peA[ks], e1 = peB[ks];
            const u32 w0 = pw0[ks], w1 = pw1[ks];
            if (more) {                        // refill slot with step s+2
                peA[ks] = *(const float4*)(ed + (s + 2) * 32);
                peB[ks] = *(const float4*)(ed + (s + 2) * 32 + 4);
                pw0[ks] = bitrow0[s + 2];
                pw1[ks] = bitrow1[s + 2];
            }
            // B fragments early: ds latency hides under p-gen
            const int chb = ((ks * 4 + g) ^ (l15 & 7)) * 8;
            const bf16x8 v0 = *(const bf16x8*)(&Bs[buf][(0 * 16 + l15) * 64 + chb]);
            const bf16x8 v1 = *(const bf16x8*)(&Bs[buf][(1 * 16 + l15) * 64 + chb]);
            const bf16x8 v2 = *(const bf16x8*)(&Bs[buf][(2 * 16 + l15) * 64 + chb]);
            const bf16x8 v3 = *(const bf16x8*)(&Bs[buf][(3 * 16 + l15) * 64 + chb]);

            f32x2 ej2[4];
            ej2[0] = f32x2{e0.x, e0.y};
            ej2[1] = f32x2{e0.z, e0.w};
            ej2[2] = f32x2{e1.x, e1.y};
            ej2[3] = f32x2{e1.z, e1.w};
            const u32 by0 = (w0 >> (8 * g)) & 0xffu;
            const u32 by1 = (w1 >> (8 * g)) & 0xffu;

            union { u32 u[4]; bf16x8 v; } af0, af1;
            #pragma unroll
            for (int qp = 0; qp < 4; ++qp) {
                f32x2 s0 = es0v + ej2[qp];
                f32x2 s1 = es1v + ej2[qp];
                s0 = __builtin_elementwise_max(s0, s0 * ALPHA);
                s1 = __builtin_elementwise_max(s1, s1 * ALPHA);
                const float p0a = fexp2(((by0 >> (2*qp))     & 1u) ? s0[0] : -1e30f);
                const float p0b = fexp2(((by0 >> (2*qp + 1)) & 1u) ? s0[1] : -1e30f);
                const float p1a = fexp2(((by1 >> (2*qp))     & 1u) ? s1[0] : -1e30f);
                const float p1b = fexp2(((by1 >> (2*qp + 1)) & 1u) ? s1[1] : -1e30f);
                union { __hip_bfloat162 b2; u32 w; } c0, c1;
                c0.b2 = __float22bfloat162_rn(make_float2(p0a, p0b));
                c1.b2 = __float22bfloat162_rn(make_float2(p1a, p1b));
                af0.u[qp] = c0.w;
                af1.u[qp] = c1.w;
            }
            __builtin_amdgcn_s_setprio(1);
            acc0[0] = __builtin_amdgcn_mfma_f32_16x16x32_bf16(af0.v, v0, acc0[0], 0, 0, 0);
            acc1[0] = __builtin_amdgcn_mfma_f32_16x16x32_bf16(af1.v, v0, acc1[0], 0, 0, 0);
            acc0[1] = __builtin_amdgcn_mfma_f32_16x16x32_bf16(af0.v, v1, acc0[1], 0, 0, 0);
            acc1[1] = __builtin_amdgcn_mfma_f32_16x16x32_bf16(af1.v, v1, acc1[1], 0, 0, 0);
            acc0[2] = __builtin_amdgcn_mfma_f32_16x16x32_bf16(af0.v, v2, acc0[2], 0, 0, 0);
            acc1[2] = __builtin_amdgcn_mfma_f32_16x16x32_bf16(af1.v, v2, acc1[2], 0, 0, 0);
            acc0[3] = __builtin_amdgcn_mfma_f32_16x16x32_bf16(af0.v, v3, acc0[3], 0, 0, 0);
            acc1[3] = __builtin_amdgcn_mfma_f32_16x16x32_bf16(af1.v, v3, acc1[3], 0, 0, 0);
            dsum0   = __builtin_amdgcn_mfma_f32_16x16x32_bf16(af0.v, ones, dsum0, 0, 0, 0);
            dsum1   = __builtin_amdgcn_mfma_f32_16x16x32_bf16(af1.v, ones, dsum1, 0, 0, 0);
            __builtin_amdgcn_s_setprio(0);
        }
        if (more) {
            // per-wave VMEM newer than the last stage load: 8 prefetches
            // -> vmcnt(8) guarantees stage landed, prefetches stay in flight.
            asm volatile("s_waitcnt vmcnt(8)" ::: "memory");
            __builtin_amdgcn_s_barrier();
        }
    }

    float inv0[4], inv1[4];
    #pragma unroll
    for (int r = 0; r < 4; ++r) { inv0[r] = 1.0f / dsum0[r]; inv1[r] = 1.0f / dsum1[r]; }
    #pragma unroll
    for (int n = 0; n < 4; ++n)
        #pragma unroll
        for (int r = 0; r < 4; ++r) {
            const int io0 = i0 + wv * 32 + g * 4 + r;
            out[(size_t)(b * NN + io0) * NH + h * 64 + n * 16 + l15] =
                acc0[n][r] * inv0[r];
            out[(size_t)(b * NN + io0 + 16) * NH + h * 64 + n * 16 + l15] =
                acc1[n][r] * inv1[r];
        }
}

// ---------------------------------------------------------------------------
extern "C" void kernel_launch(void* const* d_in, const int* in_sizes, int n_in,
                              void* d_out, int out_size, void* d_ws, size_t ws_size,
                              hipStream_t stream) {
    const float* h   = (const float*)d_in[0];
    const int*   adj = (const int*)  d_in[1];
    const float* W   = (const float*)d_in[2];
    const float* a   = (const float*)d_in[3];
    float* out = (float*)d_out;

    char* p = (char*)d_ws;
    u16*   hb   = (u16*)p;   p += (size_t)BS * NN * FIN * 2;        // 4 MB
    u16*   WbT  = (u16*)p;   p += (size_t)NH * FIN * 2;             // 256 KB
    u16*   WhT  = (u16*)p;   p += (size_t)BS * HEADS * FO * NN * 2; // 8 MB
    float* esrc = (float*)p; p += (size_t)BS * HEADS * NN * 4;      // 256 KB
    float* edst = (float*)p; p += (size_t)BS * HEADS * NN * 4;      // 256 KB
    u32*   bits = (u32*)p;                                          // 1 MB

    prep_misc<<<9248, 256, 0, stream>>>(h, adj, W, hb, WbT, bits);
    gemm_whT <<<1024, 256, 0, stream>>>(hb, WbT, a, WhT, esrc, edst);
    attn_pv  <<<512, 256, 0, stream>>>(bits, WhT, esrc, edst, out);
}